// Round 7
// baseline (375.467 us; speedup 1.0000x reference)
//
#include <hip/hip_runtime.h>
#include <math.h>

static constexpr int kB  = 16;
static constexpr int kT  = 15;
static constexpr int kH  = 480;
static constexpr int kW  = 640;
static constexpr int kCH = 16;
static constexpr int kP  = 8;
static constexpr float kEPS = 1e-5f;

// DIAGNOSTIC ROUND: k_front runs 3 identical passes (blockIdx.y), k_up runs 4
// (blockIdx.z) so both exceed the ~180us harness fills and surface in the
// rocprof top-5 with per-kernel counters. All passes write identical values.

__device__ __forceinline__ float gelu_exact(float v) {
    return 0.5f * v * (1.0f + erff(v * 0.7071067811865476f));
}

__global__ __launch_bounds__(640) void k_front(
    const float* __restrict__ x,
    const float* __restrict__ w_in, const float* __restrict__ b_in,
    const float* __restrict__ ln1_g, const float* __restrict__ ln1_b,
    const float* __restrict__ Lam_re, const float* __restrict__ Lam_im,
    const float* __restrict__ Bre, const float* __restrict__ Bim,
    const float* __restrict__ Cre, const float* __restrict__ Cim,
    const float* __restrict__ Dv, const float* __restrict__ log_step,
    const float* __restrict__ ln2_g, const float* __restrict__ ln2_b,
    const float* __restrict__ w_enc, const float* __restrict__ w_dec,
    const float* __restrict__ w_out, const float* __restrict__ b_out,
    float* __restrict__ yd)
{
    __shared__ float colsumL[kT * 80];          // [t][col4]
    __shared__ float seqL[kT * 8];              // [t][kk]
    __shared__ float xsr[64], xsi[64];          // [kk][p]
    __shared__ float f2s[128], hgs[128], x2s[128];
    __shared__ float wencT[512], wdecT[256], woutT[256];
    __shared__ float boS[16], dvS[16], g2S[16], b2S[16];
    __shared__ float cav[16], cdv[16], cg1[16], cb1[16], cag[16], cdg[16];
    __shared__ float cLr[8], cLi[8], c1r[8], c1i[8], c0r[8], c0i[8],
                     cbr[8], cbi[8], cmk[8], cst[4];
    __shared__ float cmrT[128], cmiT[128];      // [p][c]

    const int tid = threadIdx.x;
    const int blk = blockIdx.x;                 // (b*16 + i)*2 + h
    const int h   = blk & 1;
    const int bi  = blk >> 1;
    const int i   = bi & 15;
    const int b   = bi >> 4;

    if (tid < 512) wencT[(tid & 15) * 32 + (tid >> 4)] = w_enc[tid];
    if (tid < 256) {
        int jj = tid >> 4, cc = tid & 15;
        wdecT[tid] = w_dec[cc * 16 + jj];
        woutT[tid] = w_out[cc * 16 + jj];
    }
    if (tid < 16) {
        boS[tid] = b_out[tid]; dvS[tid] = Dv[tid];
        g2S[tid] = ln2_g[tid]; b2S[tid] = ln2_b[tid];
    }
    if (tid >= 544 && tid < 560) {
        int c = tid - 544;
        float mw = 0.f, mb = 0.f;
        #pragma unroll
        for (int k = 0; k < kCH; ++k) { mw += w_in[k]; mb += b_in[k]; }
        mw *= (1.f / kCH); mb *= (1.f / kCH);
        float av = w_in[c] - mw, dv = b_in[c] - mb;
        float g = ln1_g[c], bb = ln1_b[c];
        cav[c] = av; cdv[c] = dv; cg1[c] = g; cb1[c] = bb;
        cag[c] = av * g; cdg[c] = dv * g;
    } else if (tid >= 560 && tid < 568) {
        int p = tid - 560;
        float st  = expf(log_step[p]);
        float lre = Lam_re[p], lim = Lam_im[p];
        float eL  = expf(lre * st);
        cLr[p] = eL * cosf(lim * st);
        cLi[p] = eL * sinf(lim * st);
        float freq = st * fabsf(lim) * 0.15915494309189535f;
        cmk[p] = (freq < 0.25f) ? 1.f : 0.f;
    }
    __syncthreads();
    if (tid < 8) {
        int p = tid;
        float lre = Lam_re[p], lim = Lam_im[p];
        float inv = 1.f / (lre * lre + lim * lim);
        float nr = cLr[p] - 1.f, ni = cLi[p];
        float qr = (nr * lre + ni * lim) * inv;
        float qi = (ni * lre - nr * lim) * inv;
        float s1r = 0.f, s1i = 0.f, s0r = 0.f, s0i = 0.f, sbr = 0.f, sbi = 0.f;
        #pragma unroll
        for (int c = 0; c < kCH; ++c) {
            float br = Bre[p * kCH + c], bi2 = Bim[p * kCH + c];
            s1r += cag[c] * br;  s1i += cag[c] * bi2;
            s0r += cdg[c] * br;  s0i += cdg[c] * bi2;
            sbr += cb1[c] * br;  sbi += cb1[c] * bi2;
        }
        c1r[p] = qr * s1r - qi * s1i;  c1i[p] = qr * s1i + qi * s1r;
        c0r[p] = qr * s0r - qi * s0i;  c0i[p] = qr * s0i + qi * s0r;
        cbr[p] = qr * sbr - qi * sbi;  cbi[p] = qr * sbi + qi * sbr;
    } else if (tid == 8) {
        float Saa = 0.f, Sad = 0.f, Sdd = 0.f;
        #pragma unroll
        for (int c = 0; c < kCH; ++c) {
            Saa += cav[c] * cav[c];
            Sad += cav[c] * cdv[c];
            Sdd += cdv[c] * cdv[c];
        }
        cst[0] = Saa * (1.f / kCH);
        cst[1] = Sad * (1.f / kCH);
        cst[2] = Sdd * (1.f / kCH);
    } else if (tid >= 64 && tid < 192) {
        int idx = tid - 64;               // p*16 + c
        int p = idx >> 4, c = idx & 15;
        cmrT[idx] = Cre[c * kP + p] * cmk[p];
        cmiT[idx] = Cim[c * kP + p] * cmk[p];
    }

    const int fgroup = tid / 80;
    const int col4   = tid - fgroup * 80;
    const float4* __restrict__ xf4 = (const float4*)x;
    const size_t base0 = ((size_t)(b * kT) * kH + (size_t)i * 30) * 160 + h * 80 + col4;

    float accA = 0.f, accB = 0.f;
    {
        const float4* s0 = xf4 + base0 + (size_t)fgroup * (kH * 160);
        #pragma unroll
        for (int r = 0; r < 30; ++r) {
            float4 v = s0[r * 160];
            accA += (v.x + v.y) + (v.z + v.w);
        }
    }
    if (fgroup < 7) {
        const float4* s0 = xf4 + base0 + (size_t)(fgroup + 8) * (kH * 160);
        #pragma unroll
        for (int r = 0; r < 30; ++r) {
            float4 v = s0[r * 160];
            accB += (v.x + v.y) + (v.z + v.w);
        }
    }
    colsumL[fgroup * 80 + col4] = accA;
    if (fgroup < 7) colsumL[(fgroup + 8) * 80 + col4] = accB;
    __syncthreads();

    if (tid < 120) {
        int t = tid / 8, kk = tid & 7;
        float s = 0.f;
        #pragma unroll
        for (int j = 0; j < 10; ++j) s += colsumL[t * 80 + kk * 10 + j];
        seqL[t * 8 + kk] = s * (1.0f / 1200.0f);
    }
    __syncthreads();

    if (tid < 64) {
        int kk = tid >> 3, p = tid & 7;
        float Lr = cLr[p], Li = cLi[p];
        float a1r = c1r[p], a1i = c1i[p], a0r = c0r[p], a0i = c0i[p];
        float abr = cbr[p], abi = cbi[p];
        float Saa = cst[0], Sad = cst[1], Sdd = cst[2];
        float xr = 0.f, xi = 0.f;
        #pragma unroll
        for (int t = 0; t < kT; ++t) {
            float s = seqL[t * 8 + kk];
            float r = rsqrtf(s * s * Saa + 2.f * s * Sad + Sdd + kEPS);
            float be = r * s;
            float bur = be * a1r + r * a0r + abr;
            float bui = be * a1i + r * a0i + abi;
            float nr = Lr * xr - Li * xi + bur;
            float ni = Lr * xi + Li * xr + bui;
            xr = nr; xi = ni;
        }
        xsr[kk * 8 + p] = xr; xsi[kk * 8 + p] = xi;
    }
    __syncthreads();

    if (tid < 128) {
        int kk = tid >> 4, c = tid & 15;
        float s = seqL[14 * 8 + kk];
        float r = rsqrtf(s * s * cst[0] + 2.f * s * cst[1] + cst[2] + kEPS);
        float fx = (s * cav[c] + cdv[c]) * r * cg1[c] + cb1[c];
        float ys = fx * dvS[c];
        #pragma unroll
        for (int p = 0; p < kP; ++p)
            ys += xsr[kk * 8 + p] * cmrT[p * 16 + c] - xsi[kk * 8 + p] * cmiT[p * 16 + c];
        float x1 = gelu_exact(ys) + fx;
        float m = x1;
        m += __shfl_xor(m, 1); m += __shfl_xor(m, 2);
        m += __shfl_xor(m, 4); m += __shfl_xor(m, 8);
        m *= (1.f / kCH);
        float d = x1 - m;
        float v = d * d;
        v += __shfl_xor(v, 1); v += __shfl_xor(v, 2);
        v += __shfl_xor(v, 4); v += __shfl_xor(v, 8);
        v *= (1.f / kCH);
        float rs2 = rsqrtf(v + kEPS);
        f2s[tid] = d * rs2 * g2S[c] + b2S[c];
    }
    __syncthreads();
    if (tid < 128) {
        int kk = tid >> 4, j = tid & 15;
        float e1 = 0.f, e2 = 0.f;
        #pragma unroll
        for (int c = 0; c < kCH; ++c) {
            float f = f2s[kk * 16 + c];
            e1 += f * wencT[c * 32 + j];
            e2 += f * wencT[c * 32 + 16 + j];
        }
        hgs[tid] = e1 * gelu_exact(e2);
    }
    __syncthreads();
    if (tid < 128) {
        int kk = tid >> 4, c = tid & 15;
        float acc = f2s[tid];
        #pragma unroll
        for (int j = 0; j < kCH; ++j) acc += hgs[kk * 16 + j] * wdecT[j * 16 + c];
        x2s[tid] = acc;
    }
    __syncthreads();
    if (tid < 128) {
        int kk = tid >> 4, c = tid & 15;
        float acc = boS[c];
        #pragma unroll
        for (int j = 0; j < kCH; ++j) acc += x2s[kk * 16 + j] * woutT[j * 16 + c];
        yd[(b * kCH + c) * 256 + i * 16 + h * 8 + kk] = acc;
    }
}

__global__ __launch_bounds__(320) void k_up(const float* __restrict__ yd,
                                            float* __restrict__ out) {
    const int chunk = blockIdx.x;
    const int bc    = blockIdx.y;
    __shared__ float g[256];
    int tid = threadIdx.x;
    if (tid < 256) g[tid] = yd[bc * 256 + tid];
    __syncthreads();

    const int half = tid / 160;
    const int cw   = tid - half * 160;
    const int h0   = chunk * 48 + half * 24;
    const float sy = 15.0f / 479.0f;
    const float sx = 15.0f / 639.0f;

    const int px = cw * 4;
    int xa = (int)((float)px * sx);
    if (xa > 14) xa = 14;
    const int xc2 = min(xa + 2, 15);
    float A[4], Bv[4], Cv[4];
    #pragma unroll
    for (int j = 0; j < 4; ++j) {
        float rx = (float)(px + j) * sx;
        int x0 = (int)rx; if (x0 > 15) x0 = 15;
        float wx = rx - (float)x0;
        int x1 = min(x0 + 1, 15);
        int r0 = x0 - xa;
        int r1 = x1 - xa;
        A[j] = 0.f; Bv[j] = 0.f; Cv[j] = 0.f;
        float w0 = 1.f - wx;
        if (r0 == 0) A[j] += w0; else Bv[j] += w0;
        if (r1 == 1) Bv[j] += wx; else if (r1 == 2) Cv[j] += wx; else A[j] += wx;
    }

    const int ybase = (int)((float)h0 * sy);
    const int ya1 = min(ybase + 1, 15);
    const int ya2 = min(ybase + 2, 15);
    float hr0[4], hr1[4], hr2[4];
    {
        float a0 = g[ybase * 16 + xa], b0 = g[ybase * 16 + xa + 1], c0 = g[ybase * 16 + xc2];
        float a1 = g[ya1   * 16 + xa], b1 = g[ya1   * 16 + xa + 1], c1 = g[ya1   * 16 + xc2];
        float a2 = g[ya2   * 16 + xa], b2 = g[ya2   * 16 + xa + 1], c2 = g[ya2   * 16 + xc2];
        #pragma unroll
        for (int j = 0; j < 4; ++j) {
            hr0[j] = A[j] * a0 + Bv[j] * b0 + Cv[j] * c0;
            hr1[j] = A[j] * a1 + Bv[j] * b1 + Cv[j] * c1;
            hr2[j] = A[j] * a2 + Bv[j] * b2 + Cv[j] * c2;
        }
    }

    float4* dst = (float4*)(out + (size_t)bc * (kH * kW));
    #pragma unroll 4
    for (int r = 0; r < 24; ++r) {
        int ho = h0 + r;
        float ry = (float)ho * sy;
        int y0 = (int)ry;
        float wy = ry - (float)y0;
        bool up = (y0 > ybase);
        float4 res;
        #pragma unroll
        for (int j = 0; j < 4; ++j) {
            float top = up ? hr1[j] : hr0[j];
            float bot = up ? hr2[j] : hr1[j];
            ((float*)&res)[j] = top + (bot - top) * wy;
        }
        dst[ho * 160 + cw] = res;
    }
}

extern "C" void kernel_launch(void* const* d_in, const int* in_sizes, int n_in,
                              void* d_out, int out_size, void* d_ws, size_t ws_size,
                              hipStream_t stream) {
    const float* x     = (const float*)d_in[0];
    const float* w_in  = (const float*)d_in[1];
    const float* b_in  = (const float*)d_in[2];
    const float* ln1_g = (const float*)d_in[3];
    const float* ln1_b = (const float*)d_in[4];
    const float* Lre   = (const float*)d_in[5];
    const float* Lim   = (const float*)d_in[6];
    const float* Bre   = (const float*)d_in[7];
    const float* Bim   = (const float*)d_in[8];
    const float* Cre   = (const float*)d_in[9];
    const float* Cim   = (const float*)d_in[10];
    const float* Dv    = (const float*)d_in[11];
    const float* lstep = (const float*)d_in[12];
    const float* ln2_g = (const float*)d_in[13];
    const float* ln2_b = (const float*)d_in[14];
    const float* w_enc = (const float*)d_in[15];
    const float* w_dec = (const float*)d_in[16];
    const float* w_out = (const float*)d_in[17];
    const float* b_out = (const float*)d_in[18];

    float* yd  = (float*)d_ws;          // kB*kCH*256 = 65536 floats
    float* out = (float*)d_out;

    // x3 and x4 replication for rocprof surfacing (idempotent identical writes)
    k_front<<<dim3(kB * 16 * 2, 3), 640, 0, stream>>>(
        x, w_in, b_in, ln1_g, ln1_b, Lre, Lim, Bre, Bim, Cre, Cim, Dv, lstep,
        ln2_g, ln2_b, w_enc, w_dec, w_out, b_out, yd);
    k_up<<<dim3(10, kB * kCH, 4), 320, 0, stream>>>(yd, out);
}

// Round 8
// 144.612 us; speedup vs baseline: 2.5964x; 2.5964x over previous
//
#include <hip/hip_runtime.h>
#include <math.h>

static constexpr int kB  = 16;
static constexpr int kT  = 15;
static constexpr int kH  = 480;
static constexpr int kW  = 640;
static constexpr int kCH = 16;
static constexpr int kP  = 8;
static constexpr float kEPS = 1e-5f;

__device__ __forceinline__ float gelu_exact(float v) {
    return 0.5f * v * (1.0f + erff(v * 0.7071067811865476f));
}

// ---------------------------------------------------------------------------
// K1: fused downsample + SSM + head. One block per (b,i) strip, 320 threads.
// col4 = tid%160 is FIXED (320 f4 stride == 0 mod 160): the block reads its
// 15 frame-chunks (76.8 KB each) as ONE dense sequential stream; every
// wave-load is a clean 1024B line, 15 loads batched in flight per thread.
// Then: LDS reduce -> seq[15][16] -> pole-parallel scan (128 thr) ->
// channel-parallel head (256 thr) -> yd.
// ---------------------------------------------------------------------------
__global__ __launch_bounds__(320) void k_front(
    const float* __restrict__ x,
    const float* __restrict__ w_in, const float* __restrict__ b_in,
    const float* __restrict__ ln1_g, const float* __restrict__ ln1_b,
    const float* __restrict__ Lam_re, const float* __restrict__ Lam_im,
    const float* __restrict__ Bre, const float* __restrict__ Bim,
    const float* __restrict__ Cre, const float* __restrict__ Cim,
    const float* __restrict__ Dv, const float* __restrict__ log_step,
    const float* __restrict__ ln2_g, const float* __restrict__ ln2_b,
    const float* __restrict__ w_enc, const float* __restrict__ w_dec,
    const float* __restrict__ w_out, const float* __restrict__ b_out,
    float* __restrict__ yd)
{
    __shared__ float colsum[2][kT][160];     // 19.2 KB [base][t][col4]
    __shared__ float seqL[kT][16];
    __shared__ float xsr[128], xsi[128];     // [k][p]
    __shared__ float f2s[256], hgs[256], x2s[256];
    __shared__ float wencT[512], wdecT[256], woutT[256];
    __shared__ float boS[16], dvS[16], g2S[16], b2S[16];
    __shared__ float cav[16], cdv[16], cg1[16], cb1[16], cag[16], cdg[16];
    __shared__ float cLr[8], cLi[8], c1r[8], c1i[8], c0r[8], c0i[8],
                     cbr[8], cbi[8], cmk[8], cst[4];
    __shared__ float cmrT[128], cmiT[128];   // [p][c]

    const int tid = threadIdx.x;
    const int i = blockIdx.x & 15;
    const int b = blockIdx.x >> 4;

    // ---- const build step 1 ----
    if (tid < 16) {
        float mw = 0.f, mb = 0.f;
        #pragma unroll
        for (int k = 0; k < kCH; ++k) { mw += w_in[k]; mb += b_in[k]; }
        mw *= (1.f / kCH); mb *= (1.f / kCH);
        float av = w_in[tid] - mw, dv = b_in[tid] - mb;
        float g = ln1_g[tid], bb = ln1_b[tid];
        cav[tid] = av; cdv[tid] = dv; cg1[tid] = g; cb1[tid] = bb;
        cag[tid] = av * g; cdg[tid] = dv * g;
        boS[tid] = b_out[tid]; dvS[tid] = Dv[tid];
        g2S[tid] = ln2_g[tid]; b2S[tid] = ln2_b[tid];
    } else if (tid < 24) {
        int p = tid - 16;
        float st  = expf(log_step[p]);
        float lre = Lam_re[p], lim = Lam_im[p];
        float eL  = expf(lre * st);
        cLr[p] = eL * cosf(lim * st);
        cLi[p] = eL * sinf(lim * st);
        float freq = st * fabsf(lim) * 0.15915494309189535f;
        cmk[p] = (freq < 0.25f) ? 1.f : 0.f;
    }
    if (tid < 256) {
        wencT[(tid & 15) * 32 + (tid >> 4)] = w_enc[tid];
        int e2 = tid + 256;
        wencT[(e2 & 15) * 32 + (e2 >> 4)] = w_enc[e2];
        int jj = tid >> 4, cc = tid & 15;
        wdecT[tid] = w_dec[cc * 16 + jj];
        woutT[tid] = w_out[cc * 16 + jj];
    }
    __syncthreads();
    // ---- const build step 2 ----
    if (tid < 8) {
        int p = tid;
        float lre = Lam_re[p], lim = Lam_im[p];
        float inv = 1.f / (lre * lre + lim * lim);
        float nr = cLr[p] - 1.f, ni = cLi[p];
        float qr = (nr * lre + ni * lim) * inv;
        float qi = (ni * lre - nr * lim) * inv;
        float s1r = 0.f, s1i = 0.f, s0r = 0.f, s0i = 0.f, sbr = 0.f, sbi = 0.f;
        #pragma unroll
        for (int c = 0; c < kCH; ++c) {
            float br = Bre[p * kCH + c], bi2 = Bim[p * kCH + c];
            s1r += cag[c] * br;  s1i += cag[c] * bi2;
            s0r += cdg[c] * br;  s0i += cdg[c] * bi2;
            sbr += cb1[c] * br;  sbi += cb1[c] * bi2;
        }
        c1r[p] = qr * s1r - qi * s1i;  c1i[p] = qr * s1i + qi * s1r;
        c0r[p] = qr * s0r - qi * s0i;  c0i[p] = qr * s0i + qi * s0r;
        cbr[p] = qr * sbr - qi * sbi;  cbi[p] = qr * sbi + qi * sbr;
    } else if (tid == 8) {
        float Saa = 0.f, Sad = 0.f, Sdd = 0.f;
        #pragma unroll
        for (int c = 0; c < kCH; ++c) {
            Saa += cav[c] * cav[c];
            Sad += cav[c] * cdv[c];
            Sdd += cdv[c] * cdv[c];
        }
        cst[0] = Saa * (1.f / kCH);
        cst[1] = Sad * (1.f / kCH);
        cst[2] = Sdd * (1.f / kCH);
    } else if (tid >= 64 && tid < 192) {
        int idx = tid - 64;               // p*16 + c
        int p = idx >> 4, c = idx & 15;
        cmrT[idx] = Cre[c * kP + p] * cmk[p];
        cmiT[idx] = Cim[c * kP + p] * cmk[p];
    }

    // ---- dense streaming read: 15 frames x 15 steps, 15 loads in flight ----
    const int base = tid / 160;           // 0/1 (row parity pair)
    const int col4 = tid - base * 160;    // fixed f4 column
    const float4* __restrict__ xf4 = (const float4*)x;
    const size_t sbase = ((size_t)b * kT * kH + (size_t)i * 30) * 160 + tid;

    float acc[kT];
    #pragma unroll
    for (int t = 0; t < kT; ++t) acc[t] = 0.f;
    #pragma unroll
    for (int t = 0; t < kT; ++t) {
        const float4* fp = xf4 + sbase + (size_t)t * (kH * 160);
        float4 v[15];
        #pragma unroll
        for (int s = 0; s < 15; ++s) v[s] = fp[s * 320];
        float a0 = 0.f, a1 = 0.f, a2 = 0.f;
        #pragma unroll
        for (int s = 0; s < 15; s += 3) {
            a0 += (v[s].x + v[s].y) + (v[s].z + v[s].w);
            a1 += (v[s+1].x + v[s+1].y) + (v[s+1].z + v[s+1].w);
            a2 += (v[s+2].x + v[s+2].y) + (v[s+2].z + v[s+2].w);
        }
        acc[t] = (a0 + a1) + a2;
    }
    #pragma unroll
    for (int t = 0; t < kT; ++t) colsum[base][t][col4] = acc[t];
    __syncthreads();

    // ---- reduce to seq[t][k]: 240 threads ----
    if (tid < 240) {
        int t = tid >> 4, k = tid & 15;
        float s = 0.f;
        #pragma unroll
        for (int j = 0; j < 10; ++j)
            s += colsum[0][t][k * 10 + j] + colsum[1][t][k * 10 + j];
        seqL[t][k] = s * (1.0f / 1200.0f);
    }
    __syncthreads();

    // ---- SSM scan, pole-parallel: thread = (k,p), 128 threads ----
    if (tid < 128) {
        int k = tid >> 3, p = tid & 7;
        float Lr = cLr[p], Li = cLi[p];
        float a1r = c1r[p], a1i = c1i[p], a0r = c0r[p], a0i = c0i[p];
        float abr = cbr[p], abi = cbi[p];
        float Saa = cst[0], Sad = cst[1], Sdd = cst[2];
        float xr = 0.f, xi = 0.f;
        #pragma unroll
        for (int t = 0; t < kT; ++t) {
            float s = seqL[t][k];
            float r = rsqrtf(s * s * Saa + 2.f * s * Sad + Sdd + kEPS);
            float be = r * s;
            float bur = be * a1r + r * a0r + abr;
            float bui = be * a1i + r * a0i + abi;
            float nr = Lr * xr - Li * xi + bur;
            float ni = Lr * xi + Li * xr + bui;
            xr = nr; xi = ni;
        }
        xsr[k * 8 + p] = xr; xsi[k * 8 + p] = xi;
    }
    __syncthreads();

    // ---- head, channel-parallel: thread = (k,c), 256 threads ----
    if (tid < 256) {
        int k = tid >> 4, c = tid & 15;
        float s = seqL[14][k];
        float r = rsqrtf(s * s * cst[0] + 2.f * s * cst[1] + cst[2] + kEPS);
        float fx = (s * cav[c] + cdv[c]) * r * cg1[c] + cb1[c];
        float ys = fx * dvS[c];
        #pragma unroll
        for (int p = 0; p < kP; ++p)
            ys += xsr[k * 8 + p] * cmrT[p * 16 + c] - xsi[k * 8 + p] * cmiT[p * 16 + c];
        float x1 = gelu_exact(ys) + fx;
        float m = x1;
        m += __shfl_xor(m, 1); m += __shfl_xor(m, 2);
        m += __shfl_xor(m, 4); m += __shfl_xor(m, 8);
        m *= (1.f / kCH);
        float d = x1 - m;
        float v = d * d;
        v += __shfl_xor(v, 1); v += __shfl_xor(v, 2);
        v += __shfl_xor(v, 4); v += __shfl_xor(v, 8);
        v *= (1.f / kCH);
        float rs2 = rsqrtf(v + kEPS);
        f2s[tid] = d * rs2 * g2S[c] + b2S[c];
    }
    __syncthreads();
    if (tid < 256) {
        int k = tid >> 4, j = tid & 15;
        float e1 = 0.f, e2 = 0.f;
        #pragma unroll
        for (int c = 0; c < kCH; ++c) {
            float f = f2s[k * 16 + c];
            e1 += f * wencT[c * 32 + j];
            e2 += f * wencT[c * 32 + 16 + j];
        }
        hgs[tid] = e1 * gelu_exact(e2);
    }
    __syncthreads();
    if (tid < 256) {
        int k = tid >> 4, c = tid & 15;
        float acc2 = f2s[tid];
        #pragma unroll
        for (int j = 0; j < kCH; ++j) acc2 += hgs[k * 16 + j] * wdecT[j * 16 + c];
        x2s[tid] = acc2;
    }
    __syncthreads();
    if (tid < 256) {
        int k = tid >> 4, c = tid & 15;
        float acc2 = boS[c];
        #pragma unroll
        for (int j = 0; j < kCH; ++j) acc2 += x2s[k * 16 + j] * woutT[j * 16 + c];
        yd[(b * kCH + c) * 256 + i * 16 + k] = acc2;
    }
}

// ---------------------------------------------------------------------------
// K2: bilinear upsample 16x16 -> 480x640 per (b,ch). At write roofline
// (~43us for 315 MB) -- unchanged.
// ---------------------------------------------------------------------------
__global__ __launch_bounds__(320) void k_up(const float* __restrict__ yd,
                                            float* __restrict__ out) {
    const int chunk = blockIdx.x;
    const int bc    = blockIdx.y;
    __shared__ float g[256];
    int tid = threadIdx.x;
    if (tid < 256) g[tid] = yd[bc * 256 + tid];
    __syncthreads();

    const int half = tid / 160;
    const int cw   = tid - half * 160;
    const int h0   = chunk * 48 + half * 24;
    const float sy = 15.0f / 479.0f;
    const float sx = 15.0f / 639.0f;

    const int px = cw * 4;
    int xa = (int)((float)px * sx);
    if (xa > 14) xa = 14;
    const int xc2 = min(xa + 2, 15);
    float A[4], Bv[4], Cv[4];
    #pragma unroll
    for (int j = 0; j < 4; ++j) {
        float rx = (float)(px + j) * sx;
        int x0 = (int)rx; if (x0 > 15) x0 = 15;
        float wx = rx - (float)x0;
        int x1 = min(x0 + 1, 15);
        int r0 = x0 - xa;
        int r1 = x1 - xa;
        A[j] = 0.f; Bv[j] = 0.f; Cv[j] = 0.f;
        float w0 = 1.f - wx;
        if (r0 == 0) A[j] += w0; else Bv[j] += w0;
        if (r1 == 1) Bv[j] += wx; else if (r1 == 2) Cv[j] += wx; else A[j] += wx;
    }

    const int ybase = (int)((float)h0 * sy);
    const int ya1 = min(ybase + 1, 15);
    const int ya2 = min(ybase + 2, 15);
    float hr0[4], hr1[4], hr2[4];
    {
        float a0 = g[ybase * 16 + xa], b0 = g[ybase * 16 + xa + 1], c0 = g[ybase * 16 + xc2];
        float a1 = g[ya1   * 16 + xa], b1 = g[ya1   * 16 + xa + 1], c1 = g[ya1   * 16 + xc2];
        float a2 = g[ya2   * 16 + xa], b2 = g[ya2   * 16 + xa + 1], c2 = g[ya2   * 16 + xc2];
        #pragma unroll
        for (int j = 0; j < 4; ++j) {
            hr0[j] = A[j] * a0 + Bv[j] * b0 + Cv[j] * c0;
            hr1[j] = A[j] * a1 + Bv[j] * b1 + Cv[j] * c1;
            hr2[j] = A[j] * a2 + Bv[j] * b2 + Cv[j] * c2;
        }
    }

    float4* dst = (float4*)(out + (size_t)bc * (kH * kW));
    #pragma unroll 4
    for (int r = 0; r < 24; ++r) {
        int ho = h0 + r;
        float ry = (float)ho * sy;
        int y0 = (int)ry;
        float wy = ry - (float)y0;
        bool up = (y0 > ybase);
        float4 res;
        #pragma unroll
        for (int j = 0; j < 4; ++j) {
            float top = up ? hr1[j] : hr0[j];
            float bot = up ? hr2[j] : hr1[j];
            ((float*)&res)[j] = top + (bot - top) * wy;
        }
        dst[ho * 160 + cw] = res;
    }
}

extern "C" void kernel_launch(void* const* d_in, const int* in_sizes, int n_in,
                              void* d_out, int out_size, void* d_ws, size_t ws_size,
                              hipStream_t stream) {
    const float* x     = (const float*)d_in[0];
    const float* w_in  = (const float*)d_in[1];
    const float* b_in  = (const float*)d_in[2];
    const float* ln1_g = (const float*)d_in[3];
    const float* ln1_b = (const float*)d_in[4];
    const float* Lre   = (const float*)d_in[5];
    const float* Lim   = (const float*)d_in[6];
    const float* Bre   = (const float*)d_in[7];
    const float* Bim   = (const float*)d_in[8];
    const float* Cre   = (const float*)d_in[9];
    const float* Cim   = (const float*)d_in[10];
    const float* Dv    = (const float*)d_in[11];
    const float* lstep = (const float*)d_in[12];
    const float* ln2_g = (const float*)d_in[13];
    const float* ln2_b = (const float*)d_in[14];
    const float* w_enc = (const float*)d_in[15];
    const float* w_dec = (const float*)d_in[16];
    const float* w_out = (const float*)d_in[17];
    const float* b_out = (const float*)d_in[18];

    float* yd  = (float*)d_ws;          // kB*kCH*256 = 65536 floats
    float* out = (float*)d_out;

    k_front<<<kB * 16, 320, 0, stream>>>(x, w_in, b_in, ln1_g, ln1_b, Lre, Lim,
                                         Bre, Bim, Cre, Cim, Dv, lstep, ln2_g,
                                         ln2_b, w_enc, w_dec, w_out, b_out, yd);
    k_up<<<dim3(10, kB * kCH), 320, 0, stream>>>(yd, out);
}

// Round 9
// 102.586 us; speedup vs baseline: 3.6600x; 1.4097x over previous
//
#include <hip/hip_runtime.h>
#include <math.h>

static constexpr int kB  = 16;
static constexpr int kT  = 15;
static constexpr int kH  = 480;
static constexpr int kW  = 640;
static constexpr int kCH = 16;
static constexpr int kP  = 8;
static constexpr float kEPS = 1e-5f;

using f32x4 = __attribute__((ext_vector_type(4))) float;

__device__ __forceinline__ float gelu_exact(float v) {
    return 0.5f * v * (1.0f + erff(v * 0.7071067811865476f));
}

// ---------------------------------------------------------------------------
// K1: fused downsample + SSM + head. One block per (b,i) strip, 320 threads.
// Identical to round-8 EXCEPT: streaming loads are NON-TEMPORAL (nt flag,
// bypass L1/L2 allocation) to test the read-path-cap theory.
// ---------------------------------------------------------------------------
__global__ __launch_bounds__(320) void k_front(
    const float* __restrict__ x,
    const float* __restrict__ w_in, const float* __restrict__ b_in,
    const float* __restrict__ ln1_g, const float* __restrict__ ln1_b,
    const float* __restrict__ Lam_re, const float* __restrict__ Lam_im,
    const float* __restrict__ Bre, const float* __restrict__ Bim,
    const float* __restrict__ Cre, const float* __restrict__ Cim,
    const float* __restrict__ Dv, const float* __restrict__ log_step,
    const float* __restrict__ ln2_g, const float* __restrict__ ln2_b,
    const float* __restrict__ w_enc, const float* __restrict__ w_dec,
    const float* __restrict__ w_out, const float* __restrict__ b_out,
    float* __restrict__ yd)
{
    __shared__ float colsum[2][kT][160];     // 19.2 KB [base][t][col4]
    __shared__ float seqL[kT][16];
    __shared__ float xsr[128], xsi[128];     // [k][p]
    __shared__ float f2s[256], hgs[256], x2s[256];
    __shared__ float wencT[512], wdecT[256], woutT[256];
    __shared__ float boS[16], dvS[16], g2S[16], b2S[16];
    __shared__ float cav[16], cdv[16], cg1[16], cb1[16], cag[16], cdg[16];
    __shared__ float cLr[8], cLi[8], c1r[8], c1i[8], c0r[8], c0i[8],
                     cbr[8], cbi[8], cmk[8], cst[4];
    __shared__ float cmrT[128], cmiT[128];   // [p][c]

    const int tid = threadIdx.x;
    const int i = blockIdx.x & 15;
    const int b = blockIdx.x >> 4;

    // ---- const build step 1 ----
    if (tid < 16) {
        float mw = 0.f, mb = 0.f;
        #pragma unroll
        for (int k = 0; k < kCH; ++k) { mw += w_in[k]; mb += b_in[k]; }
        mw *= (1.f / kCH); mb *= (1.f / kCH);
        float av = w_in[tid] - mw, dv = b_in[tid] - mb;
        float g = ln1_g[tid], bb = ln1_b[tid];
        cav[tid] = av; cdv[tid] = dv; cg1[tid] = g; cb1[tid] = bb;
        cag[tid] = av * g; cdg[tid] = dv * g;
        boS[tid] = b_out[tid]; dvS[tid] = Dv[tid];
        g2S[tid] = ln2_g[tid]; b2S[tid] = ln2_b[tid];
    } else if (tid < 24) {
        int p = tid - 16;
        float st  = expf(log_step[p]);
        float lre = Lam_re[p], lim = Lam_im[p];
        float eL  = expf(lre * st);
        cLr[p] = eL * cosf(lim * st);
        cLi[p] = eL * sinf(lim * st);
        float freq = st * fabsf(lim) * 0.15915494309189535f;
        cmk[p] = (freq < 0.25f) ? 1.f : 0.f;
    }
    if (tid < 256) {
        wencT[(tid & 15) * 32 + (tid >> 4)] = w_enc[tid];
        int e2 = tid + 256;
        wencT[(e2 & 15) * 32 + (e2 >> 4)] = w_enc[e2];
        int jj = tid >> 4, cc = tid & 15;
        wdecT[tid] = w_dec[cc * 16 + jj];
        woutT[tid] = w_out[cc * 16 + jj];
    }
    __syncthreads();
    // ---- const build step 2 ----
    if (tid < 8) {
        int p = tid;
        float lre = Lam_re[p], lim = Lam_im[p];
        float inv = 1.f / (lre * lre + lim * lim);
        float nr = cLr[p] - 1.f, ni = cLi[p];
        float qr = (nr * lre + ni * lim) * inv;
        float qi = (ni * lre - nr * lim) * inv;
        float s1r = 0.f, s1i = 0.f, s0r = 0.f, s0i = 0.f, sbr = 0.f, sbi = 0.f;
        #pragma unroll
        for (int c = 0; c < kCH; ++c) {
            float br = Bre[p * kCH + c], bi2 = Bim[p * kCH + c];
            s1r += cag[c] * br;  s1i += cag[c] * bi2;
            s0r += cdg[c] * br;  s0i += cdg[c] * bi2;
            sbr += cb1[c] * br;  sbi += cb1[c] * bi2;
        }
        c1r[p] = qr * s1r - qi * s1i;  c1i[p] = qr * s1i + qi * s1r;
        c0r[p] = qr * s0r - qi * s0i;  c0i[p] = qr * s0i + qi * s0r;
        cbr[p] = qr * sbr - qi * sbi;  cbi[p] = qr * sbi + qi * sbr;
    } else if (tid == 8) {
        float Saa = 0.f, Sad = 0.f, Sdd = 0.f;
        #pragma unroll
        for (int c = 0; c < kCH; ++c) {
            Saa += cav[c] * cav[c];
            Sad += cav[c] * cdv[c];
            Sdd += cdv[c] * cdv[c];
        }
        cst[0] = Saa * (1.f / kCH);
        cst[1] = Sad * (1.f / kCH);
        cst[2] = Sdd * (1.f / kCH);
    } else if (tid >= 64 && tid < 192) {
        int idx = tid - 64;               // p*16 + c
        int p = idx >> 4, c = idx & 15;
        cmrT[idx] = Cre[c * kP + p] * cmk[p];
        cmiT[idx] = Cim[c * kP + p] * cmk[p];
    }

    // ---- dense streaming read (NON-TEMPORAL): 15 frames x 15 steps ----
    const int base = tid / 160;           // 0/1 (row parity pair)
    const int col4 = tid - base * 160;    // fixed f4 column
    const f32x4* __restrict__ xf4 = (const f32x4*)x;
    const size_t sbase = ((size_t)b * kT * kH + (size_t)i * 30) * 160 + tid;

    float acc[kT];
    #pragma unroll
    for (int t = 0; t < kT; ++t) acc[t] = 0.f;
    #pragma unroll
    for (int t = 0; t < kT; ++t) {
        const f32x4* fp = xf4 + sbase + (size_t)t * (kH * 160);
        f32x4 v[15];
        #pragma unroll
        for (int s = 0; s < 15; ++s) v[s] = __builtin_nontemporal_load(fp + s * 320);
        float a0 = 0.f, a1 = 0.f, a2 = 0.f;
        #pragma unroll
        for (int s = 0; s < 15; s += 3) {
            a0 += (v[s][0] + v[s][1]) + (v[s][2] + v[s][3]);
            a1 += (v[s+1][0] + v[s+1][1]) + (v[s+1][2] + v[s+1][3]);
            a2 += (v[s+2][0] + v[s+2][1]) + (v[s+2][2] + v[s+2][3]);
        }
        acc[t] = (a0 + a1) + a2;
    }
    #pragma unroll
    for (int t = 0; t < kT; ++t) colsum[base][t][col4] = acc[t];
    __syncthreads();

    // ---- reduce to seq[t][k]: 240 threads ----
    if (tid < 240) {
        int t = tid >> 4, k = tid & 15;
        float s = 0.f;
        #pragma unroll
        for (int j = 0; j < 10; ++j)
            s += colsum[0][t][k * 10 + j] + colsum[1][t][k * 10 + j];
        seqL[t][k] = s * (1.0f / 1200.0f);
    }
    __syncthreads();

    // ---- SSM scan, pole-parallel: thread = (k,p), 128 threads ----
    if (tid < 128) {
        int k = tid >> 3, p = tid & 7;
        float Lr = cLr[p], Li = cLi[p];
        float a1r = c1r[p], a1i = c1i[p], a0r = c0r[p], a0i = c0i[p];
        float abr = cbr[p], abi = cbi[p];
        float Saa = cst[0], Sad = cst[1], Sdd = cst[2];
        float xr = 0.f, xi = 0.f;
        #pragma unroll
        for (int t = 0; t < kT; ++t) {
            float s = seqL[t][k];
            float r = rsqrtf(s * s * Saa + 2.f * s * Sad + Sdd + kEPS);
            float be = r * s;
            float bur = be * a1r + r * a0r + abr;
            float bui = be * a1i + r * a0i + abi;
            float nr = Lr * xr - Li * xi + bur;
            float ni = Lr * xi + Li * xr + bui;
            xr = nr; xi = ni;
        }
        xsr[k * 8 + p] = xr; xsi[k * 8 + p] = xi;
    }
    __syncthreads();

    // ---- head, channel-parallel: thread = (k,c), 256 threads ----
    if (tid < 256) {
        int k = tid >> 4, c = tid & 15;
        float s = seqL[14][k];
        float r = rsqrtf(s * s * cst[0] + 2.f * s * cst[1] + cst[2] + kEPS);
        float fx = (s * cav[c] + cdv[c]) * r * cg1[c] + cb1[c];
        float ys = fx * dvS[c];
        #pragma unroll
        for (int p = 0; p < kP; ++p)
            ys += xsr[k * 8 + p] * cmrT[p * 16 + c] - xsi[k * 8 + p] * cmiT[p * 16 + c];
        float x1 = gelu_exact(ys) + fx;
        float m = x1;
        m += __shfl_xor(m, 1); m += __shfl_xor(m, 2);
        m += __shfl_xor(m, 4); m += __shfl_xor(m, 8);
        m *= (1.f / kCH);
        float d = x1 - m;
        float v = d * d;
        v += __shfl_xor(v, 1); v += __shfl_xor(v, 2);
        v += __shfl_xor(v, 4); v += __shfl_xor(v, 8);
        v *= (1.f / kCH);
        float rs2 = rsqrtf(v + kEPS);
        f2s[tid] = d * rs2 * g2S[c] + b2S[c];
    }
    __syncthreads();
    if (tid < 256) {
        int k = tid >> 4, j = tid & 15;
        float e1 = 0.f, e2 = 0.f;
        #pragma unroll
        for (int c = 0; c < kCH; ++c) {
            float f = f2s[k * 16 + c];
            e1 += f * wencT[c * 32 + j];
            e2 += f * wencT[c * 32 + 16 + j];
        }
        hgs[tid] = e1 * gelu_exact(e2);
    }
    __syncthreads();
    if (tid < 256) {
        int k = tid >> 4, c = tid & 15;
        float acc2 = f2s[tid];
        #pragma unroll
        for (int j = 0; j < kCH; ++j) acc2 += hgs[k * 16 + j] * wdecT[j * 16 + c];
        x2s[tid] = acc2;
    }
    __syncthreads();
    if (tid < 256) {
        int k = tid >> 4, c = tid & 15;
        float acc2 = boS[c];
        #pragma unroll
        for (int j = 0; j < kCH; ++j) acc2 += x2s[k * 16 + j] * woutT[j * 16 + c];
        yd[(b * kCH + c) * 256 + i * 16 + k] = acc2;
    }
}

// ---------------------------------------------------------------------------
// K2: bilinear upsample 16x16 -> 480x640 per (b,ch). Byte-identical to the
// round-8 version (write roofline ~43-45us).
// ---------------------------------------------------------------------------
__global__ __launch_bounds__(320) void k_up(const float* __restrict__ yd,
                                            float* __restrict__ out) {
    const int chunk = blockIdx.x;
    const int bc    = blockIdx.y;
    __shared__ float g[256];
    int tid = threadIdx.x;
    if (tid < 256) g[tid] = yd[bc * 256 + tid];
    __syncthreads();

    const int half = tid / 160;
    const int cw   = tid - half * 160;
    const int h0   = chunk * 48 + half * 24;
    const float sy = 15.0f / 479.0f;
    const float sx = 15.0f / 639.0f;

    const int px = cw * 4;
    int xa = (int)((float)px * sx);
    if (xa > 14) xa = 14;
    const int xc2 = min(xa + 2, 15);
    float A[4], Bv[4], Cv[4];
    #pragma unroll
    for (int j = 0; j < 4; ++j) {
        float rx = (float)(px + j) * sx;
        int x0 = (int)rx; if (x0 > 15) x0 = 15;
        float wx = rx - (float)x0;
        int x1 = min(x0 + 1, 15);
        int r0 = x0 - xa;
        int r1 = x1 - xa;
        A[j] = 0.f; Bv[j] = 0.f; Cv[j] = 0.f;
        float w0 = 1.f - wx;
        if (r0 == 0) A[j] += w0; else Bv[j] += w0;
        if (r1 == 1) Bv[j] += wx; else if (r1 == 2) Cv[j] += wx; else A[j] += wx;
    }

    const int ybase = (int)((float)h0 * sy);
    const int ya1 = min(ybase + 1, 15);
    const int ya2 = min(ybase + 2, 15);
    float hr0[4], hr1[4], hr2[4];
    {
        float a0 = g[ybase * 16 + xa], b0 = g[ybase * 16 + xa + 1], c0 = g[ybase * 16 + xc2];
        float a1 = g[ya1   * 16 + xa], b1 = g[ya1   * 16 + xa + 1], c1 = g[ya1   * 16 + xc2];
        float a2 = g[ya2   * 16 + xa], b2 = g[ya2   * 16 + xa + 1], c2 = g[ya2   * 16 + xc2];
        #pragma unroll
        for (int j = 0; j < 4; ++j) {
            hr0[j] = A[j] * a0 + Bv[j] * b0 + Cv[j] * c0;
            hr1[j] = A[j] * a1 + Bv[j] * b1 + Cv[j] * c1;
            hr2[j] = A[j] * a2 + Bv[j] * b2 + Cv[j] * c2;
        }
    }

    float4* dst = (float4*)(out + (size_t)bc * (kH * kW));
    #pragma unroll 4
    for (int r = 0; r < 24; ++r) {
        int ho = h0 + r;
        float ry = (float)ho * sy;
        int y0 = (int)ry;
        float wy = ry - (float)y0;
        bool up = (y0 > ybase);
        float4 res;
        #pragma unroll
        for (int j = 0; j < 4; ++j) {
            float top = up ? hr1[j] : hr0[j];
            float bot = up ? hr2[j] : hr1[j];
            ((float*)&res)[j] = top + (bot - top) * wy;
        }
        dst[ho * 160 + cw] = res;
    }
}

extern "C" void kernel_launch(void* const* d_in, const int* in_sizes, int n_in,
                              void* d_out, int out_size, void* d_ws, size_t ws_size,
                              hipStream_t stream) {
    const float* x     = (const float*)d_in[0];
    const float* w_in  = (const float*)d_in[1];
    const float* b_in  = (const float*)d_in[2];
    const float* ln1_g = (const float*)d_in[3];
    const float* ln1_b = (const float*)d_in[4];
    const float* Lre   = (const float*)d_in[5];
    const float* Lim   = (const float*)d_in[6];
    const float* Bre   = (const float*)d_in[7];
    const float* Bim   = (const float*)d_in[8];
    const float* Cre   = (const float*)d_in[9];
    const float* Cim   = (const float*)d_in[10];
    const float* Dv    = (const float*)d_in[11];
    const float* lstep = (const float*)d_in[12];
    const float* ln2_g = (const float*)d_in[13];
    const float* ln2_b = (const float*)d_in[14];
    const float* w_enc = (const float*)d_in[15];
    const float* w_dec = (const float*)d_in[16];
    const float* w_out = (const float*)d_in[17];
    const float* b_out = (const float*)d_in[18];

    float* yd  = (float*)d_ws;          // kB*kCH*256 = 65536 floats
    float* out = (float*)d_out;

    k_front<<<kB * 16, 320, 0, stream>>>(x, w_in, b_in, ln1_g, ln1_b, Lre, Lim,
                                         Bre, Bim, Cre, Cim, Dv, lstep, ln2_g,
                                         ln2_b, w_enc, w_dec, w_out, b_out, yd);
    k_up<<<dim3(10, kB * kCH), 320, 0, stream>>>(yd, out);
}